// Round 7
// baseline (824.416 us; speedup 1.0000x reference)
//
#include <hip/hip_runtime.h>
#include <stdint.h>

#define DX 1024
#define NB 64
#define DY 10
#define NJK 100

typedef unsigned short ushort_t;
typedef __attribute__((ext_vector_type(8))) short short8;
typedef __attribute__((ext_vector_type(4))) float f32x4;
typedef __attribute__((ext_vector_type(16))) float f32x16;

#define VMCNT8 asm volatile("s_waitcnt vmcnt(8)" ::: "memory")
#define VMCNT6 asm volatile("s_waitcnt vmcnt(6)" ::: "memory")
#define VMCNT5 asm volatile("s_waitcnt vmcnt(5)" ::: "memory")
#define VMCNT0 asm volatile("s_waitcnt vmcnt(0)" ::: "memory")
#define CFENCE asm volatile("" ::: "memory")

__device__ __forceinline__ unsigned short f2bf(float f) {
  unsigned int u = __builtin_bit_cast(unsigned int, f);
  u += 0x7fffu + ((u >> 16) & 1u);
  return (unsigned short)(u >> 16);
}
__device__ __forceinline__ float bf2f(unsigned short h) {
  unsigned int u = ((unsigned int)h) << 16;
  return __builtin_bit_cast(float, u);
}
__device__ __forceinline__ void gload16(const void* g, void* l) {
  __builtin_amdgcn_global_load_lds((const __attribute__((address_space(1))) unsigned int*)g,
                                   (__attribute__((address_space(3))) unsigned int*)l, 16, 0, 0);
}

// ---------------------------------------------------------------------------
// P0rho: one pass over rho per p:
//   R2[p][jk(112 pad)][m(1024)] bf16 (plain slots, 224 MiB)
//   S[p][m] = sum_j rho[p][j][m][j]  (f32, fused diagonal)
// ---------------------------------------------------------------------------
__launch_bounds__(256)
__global__ void p0_rho(const float* __restrict__ rho, ushort_t* __restrict__ R2,
                       float* __restrict__ S) {
  __shared__ ushort_t R_s[112 * 128];
  __shared__ float S_s[128];
  int p = blockIdx.x;
  int t = threadIdx.x;
  const float* rp = rho + (size_t)p * (DY * DX * DY);
  ushort_t* R2p = R2 + (size_t)p * (112 * 1024);

  for (int mc = 0; mc < 8; ++mc) {
    __syncthreads();
    if (t < 128) S_s[t] = 0.f;
    __syncthreads();
    for (int u = t; u < 6400; u += 256) {
      int j = u / 640;
      int rem = u - j * 640;
      int m = rem / 5;
      int kp = (rem - m * 5) * 2;
      const float2 v = *(const float2*)(rp + (size_t)j * (DX * DY) + (size_t)(mc * 128 + m) * DY + kp);
      int row0 = j * DY + kp;
      R_s[(row0 * 128 + m) ^ ((row0 & 15) << 3)] = f2bf(v.x);
      int row1 = row0 + 1;
      R_s[(row1 * 128 + m) ^ ((row1 & 15) << 3)] = f2bf(v.y);
      if ((j & ~1) == kp) atomicAdd(&S_s[m], (j & 1) ? v.y : v.x);
    }
    __syncthreads();
    if (t < 128) S[(size_t)p * DX + mc * 128 + t] = S_s[t];
#pragma unroll
    for (int i = 0; i < 7; ++i) {
      int c = i * 256 + t;
      int row = c >> 4, sl = c & 15;
      uint4 v = make_uint4(0u, 0u, 0u, 0u);
      if (row < NJK) v = *(const uint4*)&R_s[(row * 128 + sl * 8) ^ ((row & 15) << 3)];
      *(uint4*)(R2p + (size_t)row * 1024 + mc * 128 + sl * 8) = v;
    }
  }
}

// ---------------------------------------------------------------------------
// P0a: emit BOTH operands of K1 pre-split (per batch range given by grid):
//  XHL [b][kt(32)][m(1024)][8 slots x 16B] : record = [Ah k0..31 | Al k0..31]
//  XtHL[b][kt(32)][p(1024)][8 slots x 16B] : same for X^T rows.
// ---------------------------------------------------------------------------
__launch_bounds__(256)
__global__ void p0_split(const float* __restrict__ X,
                         ushort_t* __restrict__ XHL, ushort_t* __restrict__ XtHL) {
  __shared__ float T[64][65];
  int blk = blockIdx.x;
  int bl = blk >> 8;  // batch within this launch
  int tt = blk & 255;
  int r0 = (tt >> 4) << 6;  // X row block
  int c0 = (tt & 15) << 6;  // X col block
  const float* Xb = X + (size_t)bl * DX * DX;
  int t = threadIdx.x;
  int r = t >> 4, c = t & 15;
#pragma unroll
  for (int s = 0; s < 4; ++s) {
    const float4 v = *(const float4*)(Xb + (size_t)(r0 + r + 16 * s) * DX + c0 + c * 4);
    T[r + 16 * s][c * 4 + 0] = v.x;
    T[r + 16 * s][c * 4 + 1] = v.y;
    T[r + 16 * s][c * 4 + 2] = v.z;
    T[r + 16 * s][c * 4 + 3] = v.w;
  }
  __syncthreads();
  int s8 = t & 7;   // slot 0..7
  int rw = t >> 3;  // 0..31
  int isLo = s8 >> 2, q = s8 & 3;
#pragma unroll
  for (int ktl = 0; ktl < 2; ++ktl) {
#pragma unroll
    for (int sp = 0; sp < 2; ++sp) {
      int loc = rw + sp * 32;
      {
        unsigned short h[8];
#pragma unroll
        for (int e = 0; e < 8; ++e) {
          float x = T[loc][ktl * 32 + q * 8 + e];
          unsigned short hh = f2bf(x);
          h[e] = isLo ? f2bf(x - bf2f(hh)) : hh;
        }
        int kt = (c0 >> 5) + ktl;
        size_t off = (((size_t)bl * 32 + kt) * 1024 + (r0 + loc)) * 64 + s8 * 8;
        uint4 v;
        v.x = (unsigned)h[0] | ((unsigned)h[1] << 16);
        v.y = (unsigned)h[2] | ((unsigned)h[3] << 16);
        v.z = (unsigned)h[4] | ((unsigned)h[5] << 16);
        v.w = (unsigned)h[6] | ((unsigned)h[7] << 16);
        *(uint4*)(XHL + off) = v;
      }
      {
        unsigned short h[8];
#pragma unroll
        for (int e = 0; e < 8; ++e) {
          float x = T[ktl * 32 + q * 8 + e][loc];
          unsigned short hh = f2bf(x);
          h[e] = isLo ? f2bf(x - bf2f(hh)) : hh;
        }
        int kt = (r0 >> 5) + ktl;
        size_t off = (((size_t)bl * 32 + kt) * 1024 + (c0 + loc)) * 64 + s8 * 8;
        uint4 v;
        v.x = (unsigned)h[0] | ((unsigned)h[1] << 16);
        v.y = (unsigned)h[2] | ((unsigned)h[3] << 16);
        v.z = (unsigned)h[4] | ((unsigned)h[5] << 16);
        v.w = (unsigned)h[6] | ((unsigned)h[7] << 16);
        *(uint4*)(XtHL + off) = v;
      }
    }
  }
}

// ---------------------------------------------------------------------------
// K1: A[b]=X[b]@X[b], 3-pass split-bf16. 256x256 tile, BK=32, 8 waves (2x4),
// all staging via global_load_lds, counted vmcnt(8), raw barriers,
// setprio MFMA clusters.  Grid-size-agnostic XCD swizzle.
// Epilogue 1: EXACT trace partial = <f32 acc, S[p,m]> -> part_tr[b*16+tile].
// Epilogue 2: Ah bf16 -> [p][b][m] via LDS transpose (coalesced).
// ---------------------------------------------------------------------------
__launch_bounds__(512, 2)
__global__ void k1_gemm(const ushort_t* __restrict__ XHL,
                        const ushort_t* __restrict__ XtHL,
                        const float* __restrict__ S,
                        ushort_t* __restrict__ Ahg,
                        float* __restrict__ part_tr, int bg) {
  __shared__ ushort_t lds[65536];  // 2 bufs x (A 16384 | B 16384) ushorts
  int wg = blockIdx.x;
  int cpx = gridDim.x >> 3;
  int gt = (wg & 7) * cpx + (wg >> 3);  // XCD-chunked
  int bl = gt >> 4, tile = gt & 15;
  int b = bg + bl;
  int m0 = (tile >> 2) << 8, p0 = (tile & 3) << 8;
  int t = threadIdx.x;
  int wv = t >> 6, lane = t & 63, l31 = lane & 31, hi8 = lane >> 5;
  int wm = (wv >> 2) << 7, wp = (wv & 3) << 6;

  f32x16 acc[4][2];
#pragma unroll
  for (int mi = 0; mi < 4; ++mi)
#pragma unroll
    for (int ni = 0; ni < 2; ++ni)
#pragma unroll
      for (int e = 0; e < 16; ++e) acc[mi][ni][e] = 0.f;

  int lam = lane >> 3;          // row-within-8
  int lsl = (lane & 7) ^ lam;   // inverse-swizzled source slot
  const ushort_t* Asrc = XHL + ((size_t)bl * 32 * 1024 + m0) * 64 + (size_t)lsl * 8;
  const ushort_t* Bsrc = XtHL + ((size_t)bl * 32 * 1024 + p0) * 64 + (size_t)lsl * 8;
  int ldsw = (t & ~63) * 8;  // wave-uniform ushort offset (wv*512)

  auto stage = [&](int kt) {
    int buf = (kt & 1) << 15;
    size_t ko = (size_t)kt * 65536;
#pragma unroll
    for (int i = 0; i < 4; ++i) {
      int rr = (i << 6) + (wv << 3) + lam;
      gload16(Asrc + ko + (size_t)rr * 64, &lds[buf + (i << 12) + ldsw]);
    }
#pragma unroll
    for (int i = 0; i < 4; ++i) {
      int rr = (i << 6) + (wv << 3) + lam;
      gload16(Bsrc + ko + (size_t)rr * 64, &lds[buf + 16384 + (i << 12) + ldsw]);
    }
  };

  stage(0);
#pragma unroll 1
  for (int kt = 0; kt < 32; ++kt) {
    int buf = (kt & 1) << 15;
    if (kt < 31) {
      stage(kt + 1);
      VMCNT8;
    } else {
      VMCNT0;
    }
    __builtin_amdgcn_s_barrier();
    CFENCE;
#pragma unroll
    for (int kc = 0; kc < 2; ++kc) {
      short8 bh[2], blo[2];
#pragma unroll
      for (int ni = 0; ni < 2; ++ni) {
        int p = wp + (ni << 5) + l31;
        int rowb = buf + 16384 + p * 64;
        bh[ni] = *(const short8*)&lds[rowb + (((kc * 2 + hi8) ^ (p & 7)) << 3)];
        blo[ni] = *(const short8*)&lds[rowb + (((4 + kc * 2 + hi8) ^ (p & 7)) << 3)];
      }
#pragma unroll
      for (int mh = 0; mh < 2; ++mh) {
        short8 ah[2], al[2];
#pragma unroll
        for (int mi2 = 0; mi2 < 2; ++mi2) {
          int m = wm + ((mh * 2 + mi2) << 5) + l31;
          int rowa = buf + m * 64;
          ah[mi2] = *(const short8*)&lds[rowa + (((kc * 2 + hi8) ^ (m & 7)) << 3)];
          al[mi2] = *(const short8*)&lds[rowa + (((4 + kc * 2 + hi8) ^ (m & 7)) << 3)];
        }
        __builtin_amdgcn_s_setprio(1);
#pragma unroll
        for (int mi2 = 0; mi2 < 2; ++mi2) {
          int mi = mh * 2 + mi2;
#pragma unroll
          for (int ni = 0; ni < 2; ++ni) {
            acc[mi][ni] = __builtin_amdgcn_mfma_f32_32x32x16_bf16(ah[mi2], bh[ni], acc[mi][ni], 0, 0, 0);
            acc[mi][ni] = __builtin_amdgcn_mfma_f32_32x32x16_bf16(ah[mi2], blo[ni], acc[mi][ni], 0, 0, 0);
            acc[mi][ni] = __builtin_amdgcn_mfma_f32_32x32x16_bf16(al[mi2], bh[ni], acc[mi][ni], 0, 0, 0);
          }
        }
        __builtin_amdgcn_s_setprio(0);
      }
    }
    CFENCE;
    __builtin_amdgcn_s_barrier();
  }

  // ---- epilogue 1: EXACT trace partial from f32 accumulator ----
  float tracc = 0.f;
#pragma unroll
  for (int mi = 0; mi < 4; ++mi)
#pragma unroll
    for (int ni = 0; ni < 2; ++ni) {
      int p = p0 + wp + (ni << 5) + l31;
#pragma unroll
      for (int rg = 0; rg < 4; ++rg) {
        int m = m0 + wm + (mi << 5) + 8 * rg + 4 * hi8;
        const float4 sv = *(const float4*)(S + (size_t)p * DX + m);
        tracc += acc[mi][ni][rg * 4 + 0] * sv.x + acc[mi][ni][rg * 4 + 1] * sv.y +
                 acc[mi][ni][rg * 4 + 2] * sv.z + acc[mi][ni][rg * 4 + 3] * sv.w;
      }
    }
#pragma unroll
  for (int off = 32; off > 0; off >>= 1) tracc += __shfl_xor(tracc, off, 64);
  __syncthreads();
  if (lane == 0) ((float*)lds)[wv] = tracc;
  __syncthreads();
  if (t == 0) {
    float s = 0.f;
    for (int i = 0; i < 8; ++i) s += ((float*)lds)[i];
    part_tr[b * 16 + tile] = s;
  }
  __syncthreads();

  // ---- epilogue 2: Ah -> LDS [p][m] (swizzled) -> coalesced 16B stores ----
#pragma unroll
  for (int mi = 0; mi < 4; ++mi)
#pragma unroll
    for (int ni = 0; ni < 2; ++ni) {
      int p = wp + (ni << 5) + l31;
#pragma unroll
      for (int rg = 0; rg < 4; ++rg) {
        int m = wm + (mi << 5) + 8 * rg + 4 * hi8;
        unsigned int h0 = f2bf(acc[mi][ni][rg * 4 + 0]);
        unsigned int h1 = f2bf(acc[mi][ni][rg * 4 + 1]);
        unsigned int h2 = f2bf(acc[mi][ni][rg * 4 + 2]);
        unsigned int h3 = f2bf(acc[mi][ni][rg * 4 + 3]);
        int idx = p * 256 + (((m >> 3) ^ (p & 7)) << 3) + (m & 7);
        *(uint2*)&lds[idx] = make_uint2(h0 | (h1 << 16), h2 | (h3 << 16));
      }
    }
  __syncthreads();
#pragma unroll
  for (int i = 0; i < 16; ++i) {
    int cc = i * 512 + t;
    int row = cc >> 5, sl = cc & 31;
    int idx = row * 256 + ((sl ^ (row & 7)) << 3);
    uint4 v = *(const uint4*)&lds[idx];
    *(uint4*)(Ahg + ((size_t)(p0 + row) * NB + b) * DX + m0 + sl * 8) = v;
  }
}

// ---------------------------------------------------------------------------
// K2: numerator. One block per p: C[b,jk] += Ah[b,m]*R2[jk,m], K=1024.
// mc chunks of 64 m -> 45 KB LDS -> 3 blocks/CU. Pure gload16 staging,
// dbuf, per-wave counted vmcnt (waves 0-1: 6 loads/chunk, waves 2-3: 5).
// ---------------------------------------------------------------------------
__launch_bounds__(256)
__global__ void k2_contract(const ushort_t* __restrict__ R2,
                            const ushort_t* __restrict__ Ahg,
                            float* __restrict__ part_rho) {
  __shared__ ushort_t lds[22528];  // 2 bufs x (A 4096 | B 7168) ushorts
  int p = blockIdx.x;
  int t = threadIdx.x;
  int wv = t >> 6, lane = t & 63, lr = lane & 15, lg = lane >> 4;
  const ushort_t* R2p = R2 + (size_t)p * (112 * 1024);
  const ushort_t* Ahp = Ahg + (size_t)p * (NB * DX);

  f32x4 acc[7];
#pragma unroll
  for (int n = 0; n < 7; ++n)
#pragma unroll
    for (int i = 0; i < 4; ++i) acc[n][i] = 0.f;

  auto stage = [&](int mc) {
    int buf = (mc & 1) * 11264;
    // A: 64 b-rows x 64 m (8 slots/row), 2 loads/thread
#pragma unroll
    for (int i = 0; i < 2; ++i) {
      int c = i * 256 + t;
      int br = c >> 3, sl = c & 7;
      int lsl = sl ^ (br & 7);
      gload16(Ahp + (size_t)br * DX + mc * 64 + lsl * 8,
              &lds[buf + (i * 256 + (t & ~63)) * 8]);
    }
    // B: 112 jk-rows x 64 m, 3.5 loads/thread (waves 0-1: 4, waves 2-3: 3)
#pragma unroll
    for (int i = 0; i < 4; ++i) {
      int c = i * 256 + t;
      if (c < 896) {
        int row = c >> 3, sl = c & 7;
        int lsl = sl ^ (row & 7);
        gload16(R2p + (size_t)row * 1024 + mc * 64 + lsl * 8,
                &lds[buf + 4096 + (i * 256 + (t & ~63)) * 8]);
      }
    }
  };

  stage(0);
#pragma unroll 1
  for (int mc = 0; mc < 16; ++mc) {
    int buf = (mc & 1) * 11264;
    if (mc < 15) {
      stage(mc + 1);
      if (wv < 2) { VMCNT6; } else { VMCNT5; }
    } else {
      VMCNT0;
    }
    __builtin_amdgcn_s_barrier();
    CFENCE;
#pragma unroll
    for (int s = 0; s < 2; ++s) {
      int slot = s * 4 + lg;
      int ra = 16 * wv + lr;
      short8 af = *(const short8*)&lds[buf + ra * 64 + ((slot ^ (ra & 7)) << 3)];
      __builtin_amdgcn_s_setprio(1);
#pragma unroll
      for (int n = 0; n < 7; ++n) {
        int rb = 16 * n + lr;
        short8 bf = *(const short8*)&lds[buf + 4096 + rb * 64 + ((slot ^ (rb & 7)) << 3)];
        acc[n] = __builtin_amdgcn_mfma_f32_16x16x32_bf16(af, bf, acc[n], 0, 0, 0);
      }
      __builtin_amdgcn_s_setprio(0);
    }
    CFENCE;
    __builtin_amdgcn_s_barrier();
  }
#pragma unroll
  for (int n = 0; n < 7; ++n) {
    int col = 16 * n + lr;
    if (col < NJK) {
#pragma unroll
      for (int i = 0; i < 4; ++i) {
        int b_ = 16 * wv + lg * 4 + i;
        part_rho[((size_t)p * NB + b_) * NJK + col] = acc[n][i];
      }
    }
  }
}

// ---------------------------------------------------------------------------
// K3a: partial p-reduction; K3b: finish + divide by EXACT trace.
// ---------------------------------------------------------------------------
__launch_bounds__(128)
__global__ void k3a(const float* __restrict__ part_rho, float* __restrict__ ws2) {
  int blk = blockIdx.x;  // 128 = 64 b x 2 halves
  int b = blk >> 1, h = blk & 1;
  int t = threadIdx.x;
  if (t >= NJK) return;
  float s = 0.f;
  for (int pp = 0; pp < 512; ++pp)
    s += part_rho[((size_t)(h * 512 + pp) * NB + b) * NJK + t];
  ws2[(size_t)(h * NB + b) * 128 + t] = s;
}

__launch_bounds__(128)
__global__ void k3b(const float* __restrict__ ws2, const float* __restrict__ part_tr,
                    float* __restrict__ out) {
  int b = blockIdx.x;
  int t = threadIdx.x;
  float tr = 0.f;
#pragma unroll
  for (int i = 0; i < 16; ++i) tr += part_tr[b * 16 + i];
  if (t < NJK) {
    float v = ws2[(size_t)b * 128 + t] + ws2[(size_t)(NB + b) * 128 + t];
    out[b * NJK + t] = v / tr;
  }
}

extern "C" void kernel_launch(void* const* d_in, const int* in_sizes, int n_in,
                              void* d_out, int out_size, void* d_ws, size_t ws_size,
                              hipStream_t stream) {
  const float* X = (const float*)d_in[0];
  const float* rho = (const float*)d_in[1];
  float* out = (float*)d_out;
  char* ws = (char*)d_ws;

  const size_t MB = 1048576ull;
  const size_t need_big = 868 * MB + 65536;
  const size_t need_small = 484 * MB + 65536;

  if (ws_size >= need_big) {
    // ---- big-ws path: single p0_split + single k1 over all 64 batches ----
    ushort_t* XHL = (ushort_t*)(ws);              // 256 MiB
    ushort_t* XtHL = (ushort_t*)(ws + 256 * MB);  // 256 MiB
    ushort_t* Ahg = (ushort_t*)(ws + 512 * MB);   // 128 MiB
    ushort_t* R2 = (ushort_t*)(ws + 640 * MB);    // 224 MiB
    float* S = (float*)(ws + 864 * MB);           // 4 MiB
    float* part_tr = (float*)(ws + 868 * MB);     // 4 KiB
    float* part_rho = (float*)(ws);               // overlays XHL (dead after k1)
    float* ws2 = (float*)(ws + 32 * MB);

    hipLaunchKernelGGL(p0_rho, dim3(1024), dim3(256), 0, stream, rho, R2, S);
    hipLaunchKernelGGL(p0_split, dim3(16384), dim3(256), 0, stream, X, XHL, XtHL);
    hipLaunchKernelGGL(k1_gemm, dim3(1024), dim3(512), 0, stream, XHL, XtHL, S, Ahg, part_tr, 0);
    hipLaunchKernelGGL(k2_contract, dim3(1024), dim3(256), 0, stream, R2, Ahg, part_rho);
    hipLaunchKernelGGL(k3a, dim3(128), dim3(128), 0, stream, part_rho, ws2);
    hipLaunchKernelGGL(k3b, dim3(64), dim3(128), 0, stream, ws2, part_tr, out);
  } else {
    // ---- proven 4-group fallback (R6 structure) ----
    ushort_t* XHL = (ushort_t*)(ws);              // 64 MiB (per 16-batch group)
    ushort_t* XtHL = (ushort_t*)(ws + 64 * MB);   // 64 MiB
    ushort_t* Ahg = (ushort_t*)(ws + 128 * MB);   // 128 MiB
    ushort_t* R2 = (ushort_t*)(ws + 256 * MB);    // 224 MiB
    float* S = (float*)(ws + 480 * MB);           // 4 MiB
    float* part_tr = (float*)(ws + 484 * MB);     // 4 KiB
    float* part_rho = (float*)(ws);               // overlays XHL
    float* ws2 = (float*)(ws + 32 * MB);
    if (ws_size < need_small) return;

    hipLaunchKernelGGL(p0_rho, dim3(1024), dim3(256), 0, stream, rho, R2, S);
    for (int g = 0; g < 4; ++g) {
      hipLaunchKernelGGL(p0_split, dim3(4096), dim3(256), 0, stream,
                         X + (size_t)g * 16 * DX * DX, XHL, XtHL);
      hipLaunchKernelGGL(k1_gemm, dim3(256), dim3(512), 0, stream, XHL, XtHL, S, Ahg, part_tr, g * 16);
    }
    hipLaunchKernelGGL(k2_contract, dim3(1024), dim3(256), 0, stream, R2, Ahg, part_rho);
    hipLaunchKernelGGL(k3a, dim3(128), dim3(128), 0, stream, part_rho, ws2);
    hipLaunchKernelGGL(k3b, dim3(64), dim3(128), 0, stream, ws2, part_tr, out);
  }
}

// Round 8
// 814.195 us; speedup vs baseline: 1.0126x; 1.0126x over previous
//
#include <hip/hip_runtime.h>
#include <stdint.h>

#define DX 1024
#define NB 64
#define DY 10
#define NJK 100

typedef unsigned short ushort_t;
typedef __attribute__((ext_vector_type(8))) short short8;
typedef __attribute__((ext_vector_type(4))) float f32x4;
typedef __attribute__((ext_vector_type(16))) float f32x16;

#define VMCNT6 asm volatile("s_waitcnt vmcnt(6)" ::: "memory")
#define VMCNT5 asm volatile("s_waitcnt vmcnt(5)" ::: "memory")
#define VMCNT0 asm volatile("s_waitcnt vmcnt(0)" ::: "memory")
#define LGKM0 asm volatile("s_waitcnt lgkmcnt(0)" ::: "memory")
#define CFENCE asm volatile("" ::: "memory")

__device__ __forceinline__ unsigned short f2bf(float f) {
  unsigned int u = __builtin_bit_cast(unsigned int, f);
  u += 0x7fffu + ((u >> 16) & 1u);
  return (unsigned short)(u >> 16);
}
__device__ __forceinline__ float bf2f(unsigned short h) {
  unsigned int u = ((unsigned int)h) << 16;
  return __builtin_bit_cast(float, u);
}
__device__ __forceinline__ void gload16(const void* g, void* l) {
  __builtin_amdgcn_global_load_lds((const __attribute__((address_space(1))) unsigned int*)g,
                                   (__attribute__((address_space(3))) unsigned int*)l, 16, 0, 0);
}

// ---------------------------------------------------------------------------
// P0rho: one pass over rho per p:
//   R2[p][jk(112 pad)][m(1024)] bf16 (plain slots, 224 MiB)
//   S[p][m] = sum_j rho[p][j][m][j]  (f32, fused diagonal)
// ---------------------------------------------------------------------------
__launch_bounds__(256)
__global__ void p0_rho(const float* __restrict__ rho, ushort_t* __restrict__ R2,
                       float* __restrict__ S) {
  __shared__ ushort_t R_s[112 * 128];
  __shared__ float S_s[128];
  int p = blockIdx.x;
  int t = threadIdx.x;
  const float* rp = rho + (size_t)p * (DY * DX * DY);
  ushort_t* R2p = R2 + (size_t)p * (112 * 1024);

  for (int mc = 0; mc < 8; ++mc) {
    __syncthreads();
    if (t < 128) S_s[t] = 0.f;
    __syncthreads();
    for (int u = t; u < 6400; u += 256) {
      int j = u / 640;
      int rem = u - j * 640;
      int m = rem / 5;
      int kp = (rem - m * 5) * 2;
      const float2 v = *(const float2*)(rp + (size_t)j * (DX * DY) + (size_t)(mc * 128 + m) * DY + kp);
      int row0 = j * DY + kp;
      R_s[(row0 * 128 + m) ^ ((row0 & 15) << 3)] = f2bf(v.x);
      int row1 = row0 + 1;
      R_s[(row1 * 128 + m) ^ ((row1 & 15) << 3)] = f2bf(v.y);
      if ((j & ~1) == kp) atomicAdd(&S_s[m], (j & 1) ? v.y : v.x);
    }
    __syncthreads();
    if (t < 128) S[(size_t)p * DX + mc * 128 + t] = S_s[t];
#pragma unroll
    for (int i = 0; i < 7; ++i) {
      int c = i * 256 + t;
      int row = c >> 4, sl = c & 15;
      uint4 v = make_uint4(0u, 0u, 0u, 0u);
      if (row < NJK) v = *(const uint4*)&R_s[(row * 128 + sl * 8) ^ ((row & 15) << 3)];
      *(uint4*)(R2p + (size_t)row * 1024 + mc * 128 + sl * 8) = v;
    }
  }
}

// ---------------------------------------------------------------------------
// P0a: emit BOTH operands of K1 pre-split:
//  XHL [b][kt(32)][m(1024)][8 slots x 16B] : record = [Ah k0..31 | Al k0..31]
//  XtHL[b][kt(32)][p(1024)][8 slots x 16B] : same for X^T rows.
// ---------------------------------------------------------------------------
__launch_bounds__(256)
__global__ void p0_split(const float* __restrict__ X,
                         ushort_t* __restrict__ XHL, ushort_t* __restrict__ XtHL) {
  __shared__ float T[64][65];
  int blk = blockIdx.x;
  int bl = blk >> 8;  // batch within this launch
  int tt = blk & 255;
  int r0 = (tt >> 4) << 6;  // X row block
  int c0 = (tt & 15) << 6;  // X col block
  const float* Xb = X + (size_t)bl * DX * DX;
  int t = threadIdx.x;
  int r = t >> 4, c = t & 15;
#pragma unroll
  for (int s = 0; s < 4; ++s) {
    const float4 v = *(const float4*)(Xb + (size_t)(r0 + r + 16 * s) * DX + c0 + c * 4);
    T[r + 16 * s][c * 4 + 0] = v.x;
    T[r + 16 * s][c * 4 + 1] = v.y;
    T[r + 16 * s][c * 4 + 2] = v.z;
    T[r + 16 * s][c * 4 + 3] = v.w;
  }
  __syncthreads();
  int s8 = t & 7;   // slot 0..7
  int rw = t >> 3;  // 0..31
  int isLo = s8 >> 2, q = s8 & 3;
#pragma unroll
  for (int ktl = 0; ktl < 2; ++ktl) {
#pragma unroll
    for (int sp = 0; sp < 2; ++sp) {
      int loc = rw + sp * 32;
      {
        unsigned short h[8];
#pragma unroll
        for (int e = 0; e < 8; ++e) {
          float x = T[loc][ktl * 32 + q * 8 + e];
          unsigned short hh = f2bf(x);
          h[e] = isLo ? f2bf(x - bf2f(hh)) : hh;
        }
        int kt = (c0 >> 5) + ktl;
        size_t off = (((size_t)bl * 32 + kt) * 1024 + (r0 + loc)) * 64 + s8 * 8;
        uint4 v;
        v.x = (unsigned)h[0] | ((unsigned)h[1] << 16);
        v.y = (unsigned)h[2] | ((unsigned)h[3] << 16);
        v.z = (unsigned)h[4] | ((unsigned)h[5] << 16);
        v.w = (unsigned)h[6] | ((unsigned)h[7] << 16);
        *(uint4*)(XHL + off) = v;
      }
      {
        unsigned short h[8];
#pragma unroll
        for (int e = 0; e < 8; ++e) {
          float x = T[ktl * 32 + q * 8 + e][loc];
          unsigned short hh = f2bf(x);
          h[e] = isLo ? f2bf(x - bf2f(hh)) : hh;
        }
        int kt = (r0 >> 5) + ktl;
        size_t off = (((size_t)bl * 32 + kt) * 1024 + (c0 + loc)) * 64 + s8 * 8;
        uint4 v;
        v.x = (unsigned)h[0] | ((unsigned)h[1] << 16);
        v.y = (unsigned)h[2] | ((unsigned)h[3] << 16);
        v.z = (unsigned)h[4] | ((unsigned)h[5] << 16);
        v.w = (unsigned)h[6] | ((unsigned)h[7] << 16);
        *(uint4*)(XtHL + off) = v;
      }
    }
  }
}

// ---------------------------------------------------------------------------
// K1: A[b]=X[b]@X[b], 3-pass split-bf16, 256x256 tile, BK=32, 8 waves (2x4).
// 4-PHASE K-step (m201-style): per phase {ds_read frags, [ph1: stage kt+1],
// [ph3: vmcnt(0) — loads landed, issued 2 phases prior], s_barrier,
// lgkmcnt(0)+sched_barrier, setprio, 12 MFMA}.  Keeps layouts/epilogues.
// ---------------------------------------------------------------------------
__launch_bounds__(512, 2)
__global__ void k1_gemm(const ushort_t* __restrict__ XHL,
                        const ushort_t* __restrict__ XtHL,
                        const float* __restrict__ S,
                        ushort_t* __restrict__ Ahg,
                        float* __restrict__ part_tr, int bg) {
  __shared__ ushort_t lds[65536];  // 2 bufs x (A 16384 | B 16384) ushorts
  int wg = blockIdx.x;
  int cpx = gridDim.x >> 3;
  int gt = (wg & 7) * cpx + (wg >> 3);  // XCD-chunked
  int bl = gt >> 4, tile = gt & 15;
  int b = bg + bl;
  int m0 = (tile >> 2) << 8, p0 = (tile & 3) << 8;
  int t = threadIdx.x;
  int wv = t >> 6, lane = t & 63, l31 = lane & 31, hi8 = lane >> 5;
  int wm = (wv >> 2) << 7, wp = (wv & 3) << 6;

  f32x16 acc[4][2];
#pragma unroll
  for (int mi = 0; mi < 4; ++mi)
#pragma unroll
    for (int ni = 0; ni < 2; ++ni)
#pragma unroll
      for (int e = 0; e < 16; ++e) acc[mi][ni][e] = 0.f;

  int lam = lane >> 3;          // row-within-8
  int lsl = (lane & 7) ^ lam;   // inverse-swizzled source slot
  const ushort_t* Asrc = XHL + ((size_t)bl * 32 * 1024 + m0) * 64 + (size_t)lsl * 8;
  const ushort_t* Bsrc = XtHL + ((size_t)bl * 32 * 1024 + p0) * 64 + (size_t)lsl * 8;
  int ldsw = (t & ~63) * 8;  // wave-uniform ushort offset (wv*512)

  auto stage = [&](int kt) {
    int buf = (kt & 1) << 15;
    size_t ko = (size_t)kt * 65536;
#pragma unroll
    for (int i = 0; i < 4; ++i) {
      int rr = (i << 6) + (wv << 3) + lam;
      gload16(Asrc + ko + (size_t)rr * 64, &lds[buf + (i << 12) + ldsw]);
    }
#pragma unroll
    for (int i = 0; i < 4; ++i) {
      int rr = (i << 6) + (wv << 3) + lam;
      gload16(Bsrc + ko + (size_t)rr * 64, &lds[buf + 16384 + (i << 12) + ldsw]);
    }
  };
  // frag read helpers (ushort indices; row = 64 ushorts = 128 B, slot = 8 us)
  auto readB = [&](int buf, int kc, short8* bh, short8* blo) {
#pragma unroll
    for (int ni = 0; ni < 2; ++ni) {
      int p = wp + (ni << 5) + l31;
      int rowb = buf + 16384 + p * 64;
      bh[ni] = *(const short8*)&lds[rowb + (((kc * 2 + hi8) ^ (p & 7)) << 3)];
      blo[ni] = *(const short8*)&lds[rowb + (((4 + kc * 2 + hi8) ^ (p & 7)) << 3)];
    }
  };
  auto readA = [&](int buf, int kc, int mh, short8* ah, short8* al) {
#pragma unroll
    for (int mi2 = 0; mi2 < 2; ++mi2) {
      int m = wm + ((mh * 2 + mi2) << 5) + l31;
      int rowa = buf + m * 64;
      ah[mi2] = *(const short8*)&lds[rowa + (((kc * 2 + hi8) ^ (m & 7)) << 3)];
      al[mi2] = *(const short8*)&lds[rowa + (((4 + kc * 2 + hi8) ^ (m & 7)) << 3)];
    }
  };
  auto mfma12 = [&](int mh, const short8* ah, const short8* al,
                    const short8* bh, const short8* blo) {
    __builtin_amdgcn_s_setprio(1);
#pragma unroll
    for (int mi2 = 0; mi2 < 2; ++mi2) {
      int mi = mh * 2 + mi2;
#pragma unroll
      for (int ni = 0; ni < 2; ++ni) {
        acc[mi][ni] = __builtin_amdgcn_mfma_f32_32x32x16_bf16(ah[mi2], bh[ni], acc[mi][ni], 0, 0, 0);
        acc[mi][ni] = __builtin_amdgcn_mfma_f32_32x32x16_bf16(ah[mi2], blo[ni], acc[mi][ni], 0, 0, 0);
        acc[mi][ni] = __builtin_amdgcn_mfma_f32_32x32x16_bf16(al[mi2], bh[ni], acc[mi][ni], 0, 0, 0);
      }
    }
    __builtin_amdgcn_s_setprio(0);
  };

  // prologue: stage tile 0 fully, drain, sync
  stage(0);
  VMCNT0;
  __builtin_amdgcn_s_barrier();

#pragma unroll 1
  for (int kt = 0; kt < 32; ++kt) {
    int buf = (kt & 1) << 15;
    short8 bh[2], blo[2], ah[2], al[2];
    // ---- phase 0: kc=0, mh=0 ----
    readB(buf, 0, bh, blo);
    readA(buf, 0, 0, ah, al);
    CFENCE;
    __builtin_amdgcn_s_barrier();
    LGKM0;
    __builtin_amdgcn_sched_barrier(0);
    mfma12(0, ah, al, bh, blo);
    // ---- phase 1: kc=0, mh=1  (+ stage kt+1) ----
    readA(buf, 0, 1, ah, al);
    if (kt < 31) stage(kt + 1);
    CFENCE;
    __builtin_amdgcn_s_barrier();
    LGKM0;
    __builtin_amdgcn_sched_barrier(0);
    mfma12(1, ah, al, bh, blo);
    // ---- phase 2: kc=1, mh=0 ----
    readB(buf, 1, bh, blo);
    readA(buf, 1, 0, ah, al);
    CFENCE;
    __builtin_amdgcn_s_barrier();
    LGKM0;
    __builtin_amdgcn_sched_barrier(0);
    mfma12(0, ah, al, bh, blo);
    // ---- phase 3: kc=1, mh=1  (+ vmcnt(0): stage landed, issued 2 ph ago) ----
    readA(buf, 1, 1, ah, al);
    VMCNT0;
    CFENCE;
    __builtin_amdgcn_s_barrier();
    LGKM0;
    __builtin_amdgcn_sched_barrier(0);
    mfma12(1, ah, al, bh, blo);
  }

  // ---- epilogue 1: EXACT trace partial from f32 accumulator ----
  float tracc = 0.f;
#pragma unroll
  for (int mi = 0; mi < 4; ++mi)
#pragma unroll
    for (int ni = 0; ni < 2; ++ni) {
      int p = p0 + wp + (ni << 5) + l31;
#pragma unroll
      for (int rg = 0; rg < 4; ++rg) {
        int m = m0 + wm + (mi << 5) + 8 * rg + 4 * hi8;
        const float4 sv = *(const float4*)(S + (size_t)p * DX + m);
        tracc += acc[mi][ni][rg * 4 + 0] * sv.x + acc[mi][ni][rg * 4 + 1] * sv.y +
                 acc[mi][ni][rg * 4 + 2] * sv.z + acc[mi][ni][rg * 4 + 3] * sv.w;
      }
    }
#pragma unroll
  for (int off = 32; off > 0; off >>= 1) tracc += __shfl_xor(tracc, off, 64);
  __syncthreads();
  if (lane == 0) ((float*)lds)[wv] = tracc;
  __syncthreads();
  if (t == 0) {
    float s = 0.f;
    for (int i = 0; i < 8; ++i) s += ((float*)lds)[i];
    part_tr[b * 16 + tile] = s;
  }
  __syncthreads();

  // ---- epilogue 2: Ah -> LDS [p][m] (swizzled) -> coalesced 16B stores ----
#pragma unroll
  for (int mi = 0; mi < 4; ++mi)
#pragma unroll
    for (int ni = 0; ni < 2; ++ni) {
      int p = wp + (ni << 5) + l31;
#pragma unroll
      for (int rg = 0; rg < 4; ++rg) {
        int m = wm + (mi << 5) + 8 * rg + 4 * hi8;
        unsigned int h0 = f2bf(acc[mi][ni][rg * 4 + 0]);
        unsigned int h1 = f2bf(acc[mi][ni][rg * 4 + 1]);
        unsigned int h2 = f2bf(acc[mi][ni][rg * 4 + 2]);
        unsigned int h3 = f2bf(acc[mi][ni][rg * 4 + 3]);
        int idx = p * 256 + (((m >> 3) ^ (p & 7)) << 3) + (m & 7);
        *(uint2*)&lds[idx] = make_uint2(h0 | (h1 << 16), h2 | (h3 << 16));
      }
    }
  __syncthreads();
#pragma unroll
  for (int i = 0; i < 16; ++i) {
    int cc = i * 512 + t;
    int row = cc >> 5, sl = cc & 31;
    int idx = row * 256 + ((sl ^ (row & 7)) << 3);
    uint4 v = *(const uint4*)&lds[idx];
    *(uint4*)(Ahg + ((size_t)(p0 + row) * NB + b) * DX + m0 + sl * 8) = v;
  }
}

// ---------------------------------------------------------------------------
// K2: numerator. One block per p: C[b,jk] += Ah[b,m]*R2[jk,m], K=1024.
// mc chunks of 64 m -> 45 KB LDS -> 3 blocks/CU. Pure gload16 staging,
// dbuf, per-wave counted vmcnt (waves 0-1: 6 loads/chunk, waves 2-3: 5).
// ---------------------------------------------------------------------------
__launch_bounds__(256)
__global__ void k2_contract(const ushort_t* __restrict__ R2,
                            const ushort_t* __restrict__ Ahg,
                            float* __restrict__ part_rho) {
  __shared__ ushort_t lds[22528];  // 2 bufs x (A 4096 | B 7168) ushorts
  int p = blockIdx.x;
  int t = threadIdx.x;
  int wv = t >> 6, lane = t & 63, lr = lane & 15, lg = lane >> 4;
  const ushort_t* R2p = R2 + (size_t)p * (112 * 1024);
  const ushort_t* Ahp = Ahg + (size_t)p * (NB * DX);

  f32x4 acc[7];
#pragma unroll
  for (int n = 0; n < 7; ++n)
#pragma unroll
    for (int i = 0; i < 4; ++i) acc[n][i] = 0.f;

  auto stage = [&](int mc) {
    int buf = (mc & 1) * 11264;
#pragma unroll
    for (int i = 0; i < 2; ++i) {
      int c = i * 256 + t;
      int br = c >> 3, sl = c & 7;
      int lsl = sl ^ (br & 7);
      gload16(Ahp + (size_t)br * DX + mc * 64 + lsl * 8,
              &lds[buf + (i * 256 + (t & ~63)) * 8]);
    }
#pragma unroll
    for (int i = 0; i < 4; ++i) {
      int c = i * 256 + t;
      if (c < 896) {
        int row = c >> 3, sl = c & 7;
        int lsl = sl ^ (row & 7);
        gload16(R2p + (size_t)row * 1024 + mc * 64 + lsl * 8,
                &lds[buf + 4096 + (i * 256 + (t & ~63)) * 8]);
      }
    }
  };

  stage(0);
#pragma unroll 1
  for (int mc = 0; mc < 16; ++mc) {
    int buf = (mc & 1) * 11264;
    if (mc < 15) {
      stage(mc + 1);
      if (wv < 2) { VMCNT6; } else { VMCNT5; }
    } else {
      VMCNT0;
    }
    __builtin_amdgcn_s_barrier();
    CFENCE;
#pragma unroll
    for (int s = 0; s < 2; ++s) {
      int slot = s * 4 + lg;
      int ra = 16 * wv + lr;
      short8 af = *(const short8*)&lds[buf + ra * 64 + ((slot ^ (ra & 7)) << 3)];
      __builtin_amdgcn_s_setprio(1);
#pragma unroll
      for (int n = 0; n < 7; ++n) {
        int rb = 16 * n + lr;
        short8 bf = *(const short8*)&lds[buf + 4096 + rb * 64 + ((slot ^ (rb & 7)) << 3)];
        acc[n] = __builtin_amdgcn_mfma_f32_16x16x32_bf16(af, bf, acc[n], 0, 0, 0);
      }
      __builtin_amdgcn_s_setprio(0);
    }
    CFENCE;
    __builtin_amdgcn_s_barrier();
  }
#pragma unroll
  for (int n = 0; n < 7; ++n) {
    int col = 16 * n + lr;
    if (col < NJK) {
#pragma unroll
      for (int i = 0; i < 4; ++i) {
        int b_ = 16 * wv + lg * 4 + i;
        part_rho[((size_t)p * NB + b_) * NJK + col] = acc[n][i];
      }
    }
  }
}

// ---------------------------------------------------------------------------
// K3a: partial p-reduction; K3b: finish + divide by EXACT trace.
// ---------------------------------------------------------------------------
__launch_bounds__(128)
__global__ void k3a(const float* __restrict__ part_rho, float* __restrict__ ws2) {
  int blk = blockIdx.x;  // 128 = 64 b x 2 halves
  int b = blk >> 1, h = blk & 1;
  int t = threadIdx.x;
  if (t >= NJK) return;
  float s = 0.f;
  for (int pp = 0; pp < 512; ++pp)
    s += part_rho[((size_t)(h * 512 + pp) * NB + b) * NJK + t];
  ws2[(size_t)(h * NB + b) * 128 + t] = s;
}

__launch_bounds__(128)
__global__ void k3b(const float* __restrict__ ws2, const float* __restrict__ part_tr,
                    float* __restrict__ out) {
  int b = blockIdx.x;
  int t = threadIdx.x;
  float tr = 0.f;
#pragma unroll
  for (int i = 0; i < 16; ++i) tr += part_tr[b * 16 + i];
  if (t < NJK) {
    float v = ws2[(size_t)b * 128 + t] + ws2[(size_t)(NB + b) * 128 + t];
    out[b * NJK + t] = v / tr;
  }
}

extern "C" void kernel_launch(void* const* d_in, const int* in_sizes, int n_in,
                              void* d_out, int out_size, void* d_ws, size_t ws_size,
                              hipStream_t stream) {
  const float* X = (const float*)d_in[0];
  const float* rho = (const float*)d_in[1];
  float* out = (float*)d_out;
  char* ws = (char*)d_ws;

  const size_t MB = 1048576ull;
  const size_t need_big = 868 * MB + 65536;
  const size_t need_small = 484 * MB + 65536;

  if (ws_size >= need_big) {
    ushort_t* XHL = (ushort_t*)(ws);              // 256 MiB
    ushort_t* XtHL = (ushort_t*)(ws + 256 * MB);  // 256 MiB
    ushort_t* Ahg = (ushort_t*)(ws + 512 * MB);   // 128 MiB
    ushort_t* R2 = (ushort_t*)(ws + 640 * MB);    // 224 MiB
    float* S = (float*)(ws + 864 * MB);           // 4 MiB
    float* part_tr = (float*)(ws + 868 * MB);     // 4 KiB
    float* part_rho = (float*)(ws);               // overlays XHL (dead after k1)
    float* ws2 = (float*)(ws + 32 * MB);

    hipLaunchKernelGGL(p0_rho, dim3(1024), dim3(256), 0, stream, rho, R2, S);
    hipLaunchKernelGGL(p0_split, dim3(16384), dim3(256), 0, stream, X, XHL, XtHL);
    hipLaunchKernelGGL(k1_gemm, dim3(1024), dim3(512), 0, stream, XHL, XtHL, S, Ahg, part_tr, 0);
    hipLaunchKernelGGL(k2_contract, dim3(1024), dim3(256), 0, stream, R2, Ahg, part_rho);
    hipLaunchKernelGGL(k3a, dim3(128), dim3(128), 0, stream, part_rho, ws2);
    hipLaunchKernelGGL(k3b, dim3(64), dim3(128), 0, stream, ws2, part_tr, out);
  } else {
    ushort_t* XHL = (ushort_t*)(ws);              // 64 MiB (per 16-batch group)
    ushort_t* XtHL = (ushort_t*)(ws + 64 * MB);   // 64 MiB
    ushort_t* Ahg = (ushort_t*)(ws + 128 * MB);   // 128 MiB
    ushort_t* R2 = (ushort_t*)(ws + 256 * MB);    // 224 MiB
    float* S = (float*)(ws + 480 * MB);           // 4 MiB
    float* part_tr = (float*)(ws + 484 * MB);     // 4 KiB
    float* part_rho = (float*)(ws);               // overlays XHL
    float* ws2 = (float*)(ws + 32 * MB);
    if (ws_size < need_small) return;

    hipLaunchKernelGGL(p0_rho, dim3(1024), dim3(256), 0, stream, rho, R2, S);
    for (int g = 0; g < 4; ++g) {
      hipLaunchKernelGGL(p0_split, dim3(4096), dim3(256), 0, stream,
                         X + (size_t)g * 16 * DX * DX, XHL, XtHL);
      hipLaunchKernelGGL(k1_gemm, dim3(256), dim3(512), 0, stream, XHL, XtHL, S, Ahg, part_tr, g * 16);
    }
    hipLaunchKernelGGL(k2_contract, dim3(1024), dim3(256), 0, stream, R2, Ahg, part_rho);
    hipLaunchKernelGGL(k3a, dim3(128), dim3(128), 0, stream, part_rho, ws2);
    hipLaunchKernelGGL(k3b, dim3(64), dim3(128), 0, stream, ws2, part_tr, out);
  }
}

// Round 9
// 737.582 us; speedup vs baseline: 1.1177x; 1.1039x over previous
//
#include <hip/hip_runtime.h>
#include <stdint.h>

#define DX 1024
#define NB 64
#define DY 10
#define NJK 100

typedef unsigned short ushort_t;
typedef __attribute__((ext_vector_type(8))) short short8;
typedef __attribute__((ext_vector_type(4))) float f32x4;
typedef __attribute__((ext_vector_type(16))) float f32x16;

#define VMCNT6 asm volatile("s_waitcnt vmcnt(6)" ::: "memory")
#define VMCNT5 asm volatile("s_waitcnt vmcnt(5)" ::: "memory")
#define VMCNT4 asm volatile("s_waitcnt vmcnt(4)" ::: "memory")
#define VMCNT0 asm volatile("s_waitcnt vmcnt(0)" ::: "memory")
#define LGKM0 asm volatile("s_waitcnt lgkmcnt(0)" ::: "memory")
#define CFENCE asm volatile("" ::: "memory")

__device__ __forceinline__ unsigned short f2bf(float f) {
  unsigned int u = __builtin_bit_cast(unsigned int, f);
  u += 0x7fffu + ((u >> 16) & 1u);
  return (unsigned short)(u >> 16);
}
__device__ __forceinline__ float bf2f(unsigned short h) {
  unsigned int u = ((unsigned int)h) << 16;
  return __builtin_bit_cast(float, u);
}
__device__ __forceinline__ void gload16(const void* g, void* l) {
  __builtin_amdgcn_global_load_lds((const __attribute__((address_space(1))) unsigned int*)g,
                                   (__attribute__((address_space(3))) unsigned int*)l, 16, 0, 0);
}

// ---------------------------------------------------------------------------
// P0rho: one pass over rho per p:
//   R2[p][jk(112 pad)][m(1024)] bf16 (plain slots, 224 MiB)
//   S[p][m] = sum_j rho[p][j][m][j]  (f32, fused diagonal, shfl-paired)
// Div-free staging: thread -> (m = t>>1, h = t&1); per j: float4 + float.
// ---------------------------------------------------------------------------
__launch_bounds__(256)
__global__ void p0_rho(const float* __restrict__ rho, ushort_t* __restrict__ R2,
                       float* __restrict__ S) {
  __shared__ ushort_t R_s[112 * 128];
  int p = blockIdx.x;
  int t = threadIdx.x;
  const float* rp = rho + (size_t)p * (DY * DX * DY);
  ushort_t* R2p = R2 + (size_t)p * (112 * 1024);
  int m = t >> 1, h = t & 1;

  for (int mc = 0; mc < 8; ++mc) {
    __syncthreads();  // previous chunk's readback complete
    float ssum = 0.f;
#pragma unroll
    for (int j = 0; j < DY; ++j) {
      const float* bj = rp + (size_t)j * (DX * DY) + (size_t)(mc * 128 + m) * DY;
      const float4 q = *(const float4*)(bj + h * 4);
      const float e = bj[8 + h];
      int rb = j * DY + h * 4;
      R_s[((rb + 0) * 128 + m) ^ (((rb + 0) & 15) << 3)] = f2bf(q.x);
      R_s[((rb + 1) * 128 + m) ^ (((rb + 1) & 15) << 3)] = f2bf(q.y);
      R_s[((rb + 2) * 128 + m) ^ (((rb + 2) & 15) << 3)] = f2bf(q.z);
      R_s[((rb + 3) * 128 + m) ^ (((rb + 3) & 15) << 3)] = f2bf(q.w);
      int r8 = j * DY + 8 + h;
      R_s[(r8 * 128 + m) ^ ((r8 & 15) << 3)] = f2bf(e);
      if (h == 0) {
        if (j == 0) ssum += q.x;
        if (j == 1) ssum += q.y;
        if (j == 2) ssum += q.z;
        if (j == 3) ssum += q.w;
        if (j == 8) ssum += e;
      } else {
        if (j == 4) ssum += q.x;
        if (j == 5) ssum += q.y;
        if (j == 6) ssum += q.z;
        if (j == 7) ssum += q.w;
        if (j == 9) ssum += e;
      }
    }
    ssum += __shfl_xor(ssum, 1, 64);
    if (h == 0) S[(size_t)p * DX + mc * 128 + m] = ssum;
    __syncthreads();
#pragma unroll
    for (int i = 0; i < 7; ++i) {
      int c = i * 256 + t;
      int row = c >> 4, sl = c & 15;
      uint4 v = make_uint4(0u, 0u, 0u, 0u);
      if (row < NJK) v = *(const uint4*)&R_s[(row * 128 + sl * 8) ^ ((row & 15) << 3)];
      *(uint4*)(R2p + (size_t)row * 1024 + mc * 128 + sl * 8) = v;
    }
  }
}

// ---------------------------------------------------------------------------
// P0a: emit BOTH operands of K1 pre-split:
//  XHL [b][kt(32)][m(1024)][8 slots x 16B] : record = [Ah k0..31 | Al k0..31]
//  XtHL[b][kt(32)][p(1024)][8 slots x 16B] : same for X^T rows.
// ---------------------------------------------------------------------------
__launch_bounds__(256)
__global__ void p0_split(const float* __restrict__ X,
                         ushort_t* __restrict__ XHL, ushort_t* __restrict__ XtHL) {
  __shared__ float T[64][65];
  int blk = blockIdx.x;
  int bl = blk >> 8;  // batch within this launch
  int tt = blk & 255;
  int r0 = (tt >> 4) << 6;  // X row block
  int c0 = (tt & 15) << 6;  // X col block
  const float* Xb = X + (size_t)bl * DX * DX;
  int t = threadIdx.x;
  int r = t >> 4, c = t & 15;
#pragma unroll
  for (int s = 0; s < 4; ++s) {
    const float4 v = *(const float4*)(Xb + (size_t)(r0 + r + 16 * s) * DX + c0 + c * 4);
    T[r + 16 * s][c * 4 + 0] = v.x;
    T[r + 16 * s][c * 4 + 1] = v.y;
    T[r + 16 * s][c * 4 + 2] = v.z;
    T[r + 16 * s][c * 4 + 3] = v.w;
  }
  __syncthreads();
  int s8 = t & 7;   // slot 0..7
  int rw = t >> 3;  // 0..31
  int isLo = s8 >> 2, q = s8 & 3;
#pragma unroll
  for (int ktl = 0; ktl < 2; ++ktl) {
#pragma unroll
    for (int sp = 0; sp < 2; ++sp) {
      int loc = rw + sp * 32;
      {
        unsigned short hh8[8];
#pragma unroll
        for (int e = 0; e < 8; ++e) {
          float x = T[loc][ktl * 32 + q * 8 + e];
          unsigned short hh = f2bf(x);
          hh8[e] = isLo ? f2bf(x - bf2f(hh)) : hh;
        }
        int kt = (c0 >> 5) + ktl;
        size_t off = (((size_t)bl * 32 + kt) * 1024 + (r0 + loc)) * 64 + s8 * 8;
        uint4 v;
        v.x = (unsigned)hh8[0] | ((unsigned)hh8[1] << 16);
        v.y = (unsigned)hh8[2] | ((unsigned)hh8[3] << 16);
        v.z = (unsigned)hh8[4] | ((unsigned)hh8[5] << 16);
        v.w = (unsigned)hh8[6] | ((unsigned)hh8[7] << 16);
        *(uint4*)(XHL + off) = v;
      }
      {
        unsigned short hh8[8];
#pragma unroll
        for (int e = 0; e < 8; ++e) {
          float x = T[ktl * 32 + q * 8 + e][loc];
          unsigned short hh = f2bf(x);
          hh8[e] = isLo ? f2bf(x - bf2f(hh)) : hh;
        }
        int kt = (r0 >> 5) + ktl;
        size_t off = (((size_t)bl * 32 + kt) * 1024 + (c0 + loc)) * 64 + s8 * 8;
        uint4 v;
        v.x = (unsigned)hh8[0] | ((unsigned)hh8[1] << 16);
        v.y = (unsigned)hh8[2] | ((unsigned)hh8[3] << 16);
        v.z = (unsigned)hh8[4] | ((unsigned)hh8[5] << 16);
        v.w = (unsigned)hh8[6] | ((unsigned)hh8[7] << 16);
        *(uint4*)(XtHL + off) = v;
      }
    }
  }
}

// ---------------------------------------------------------------------------
// K1: A[b]=X[b]@X[b], 3-pass split-bf16, 256x256 tile, BK=32, 8 waves (2x4).
// 4-phase K-step; stage split A@ph0 / B@ph1 (4 gloads each, spreads L2 burst);
// counted drains: vmcnt(4) @ph2-end (A of kt+1), vmcnt(0) @ph3-end (B, age 2
// phases).  Raw barriers; lgkm0+sched_barrier; setprio MFMA clusters.
// ---------------------------------------------------------------------------
__launch_bounds__(512, 2)
__global__ void k1_gemm(const ushort_t* __restrict__ XHL,
                        const ushort_t* __restrict__ XtHL,
                        const float* __restrict__ S,
                        ushort_t* __restrict__ Ahg,
                        float* __restrict__ part_tr, int bg) {
  __shared__ ushort_t lds[65536];  // 2 bufs x (A 16384 | B 16384) ushorts
  int wg = blockIdx.x;
  int cpx = gridDim.x >> 3;
  int gt = (wg & 7) * cpx + (wg >> 3);  // XCD-chunked
  int bl = gt >> 4, tile = gt & 15;
  int b = bg + bl;
  int m0 = (tile >> 2) << 8, p0 = (tile & 3) << 8;
  int t = threadIdx.x;
  int wv = t >> 6, lane = t & 63, l31 = lane & 31, hi8 = lane >> 5;
  int wm = (wv >> 2) << 7, wp = (wv & 3) << 6;

  f32x16 acc[4][2];
#pragma unroll
  for (int mi = 0; mi < 4; ++mi)
#pragma unroll
    for (int ni = 0; ni < 2; ++ni)
#pragma unroll
      for (int e = 0; e < 16; ++e) acc[mi][ni][e] = 0.f;

  int lam = lane >> 3;          // row-within-8
  int lsl = (lane & 7) ^ lam;   // inverse-swizzled source slot
  const ushort_t* Asrc = XHL + ((size_t)bl * 32 * 1024 + m0) * 64 + (size_t)lsl * 8;
  const ushort_t* Bsrc = XtHL + ((size_t)bl * 32 * 1024 + p0) * 64 + (size_t)lsl * 8;
  int ldsw = (t & ~63) * 8;  // wave-uniform ushort offset (wv*512)

  auto stageA = [&](int kt) {
    int buf = (kt & 1) << 15;
    size_t ko = (size_t)kt * 65536;
#pragma unroll
    for (int i = 0; i < 4; ++i) {
      int rr = (i << 6) + (wv << 3) + lam;
      gload16(Asrc + ko + (size_t)rr * 64, &lds[buf + (i << 12) + ldsw]);
    }
  };
  auto stageB = [&](int kt) {
    int buf = (kt & 1) << 15;
    size_t ko = (size_t)kt * 65536;
#pragma unroll
    for (int i = 0; i < 4; ++i) {
      int rr = (i << 6) + (wv << 3) + lam;
      gload16(Bsrc + ko + (size_t)rr * 64, &lds[buf + 16384 + (i << 12) + ldsw]);
    }
  };
  auto readB = [&](int buf, int kc, short8* bh, short8* blo) {
#pragma unroll
    for (int ni = 0; ni < 2; ++ni) {
      int p = wp + (ni << 5) + l31;
      int rowb = buf + 16384 + p * 64;
      bh[ni] = *(const short8*)&lds[rowb + (((kc * 2 + hi8) ^ (p & 7)) << 3)];
      blo[ni] = *(const short8*)&lds[rowb + (((4 + kc * 2 + hi8) ^ (p & 7)) << 3)];
    }
  };
  auto readA = [&](int buf, int kc, int mh, short8* ah, short8* al) {
#pragma unroll
    for (int mi2 = 0; mi2 < 2; ++mi2) {
      int m = wm + ((mh * 2 + mi2) << 5) + l31;
      int rowa = buf + m * 64;
      ah[mi2] = *(const short8*)&lds[rowa + (((kc * 2 + hi8) ^ (m & 7)) << 3)];
      al[mi2] = *(const short8*)&lds[rowa + (((4 + kc * 2 + hi8) ^ (m & 7)) << 3)];
    }
  };
  auto mfma12 = [&](int mh, const short8* ah, const short8* al,
                    const short8* bh, const short8* blo) {
    __builtin_amdgcn_s_setprio(1);
#pragma unroll
    for (int mi2 = 0; mi2 < 2; ++mi2) {
      int mi = mh * 2 + mi2;
#pragma unroll
      for (int ni = 0; ni < 2; ++ni) {
        acc[mi][ni] = __builtin_amdgcn_mfma_f32_32x32x16_bf16(ah[mi2], bh[ni], acc[mi][ni], 0, 0, 0);
        acc[mi][ni] = __builtin_amdgcn_mfma_f32_32x32x16_bf16(ah[mi2], blo[ni], acc[mi][ni], 0, 0, 0);
        acc[mi][ni] = __builtin_amdgcn_mfma_f32_32x32x16_bf16(al[mi2], bh[ni], acc[mi][ni], 0, 0, 0);
      }
    }
    __builtin_amdgcn_s_setprio(0);
  };

  // prologue: stage tile 0 fully, drain, sync
  stageA(0);
  stageB(0);
  VMCNT0;
  __builtin_amdgcn_s_barrier();

#pragma unroll 1
  for (int kt = 0; kt < 32; ++kt) {
    int buf = (kt & 1) << 15;
    short8 bh[2], blo[2], ah[2], al[2];
    // ---- phase 0: kc=0, mh=0  (+ stage A of kt+1) ----
    readB(buf, 0, bh, blo);
    readA(buf, 0, 0, ah, al);
    if (kt < 31) stageA(kt + 1);
    CFENCE;
    __builtin_amdgcn_s_barrier();
    LGKM0;
    __builtin_amdgcn_sched_barrier(0);
    mfma12(0, ah, al, bh, blo);
    // ---- phase 1: kc=0, mh=1  (+ stage B of kt+1) ----
    readA(buf, 0, 1, ah, al);
    if (kt < 31) stageB(kt + 1);
    CFENCE;
    __builtin_amdgcn_s_barrier();
    LGKM0;
    __builtin_amdgcn_sched_barrier(0);
    mfma12(1, ah, al, bh, blo);
    // ---- phase 2: kc=1, mh=0  (+ vmcnt(4): A(kt+1) landed, B in flight) ----
    readB(buf, 1, bh, blo);
    readA(buf, 1, 0, ah, al);
    VMCNT4;
    CFENCE;
    __builtin_amdgcn_s_barrier();
    LGKM0;
    __builtin_amdgcn_sched_barrier(0);
    mfma12(0, ah, al, bh, blo);
    // ---- phase 3: kc=1, mh=1  (+ vmcnt(0): B(kt+1), age 2 phases) ----
    readA(buf, 1, 1, ah, al);
    VMCNT0;
    CFENCE;
    __builtin_amdgcn_s_barrier();
    LGKM0;
    __builtin_amdgcn_sched_barrier(0);
    mfma12(1, ah, al, bh, blo);
  }

  // ---- epilogue 1: EXACT trace partial from f32 accumulator ----
  float tracc = 0.f;
#pragma unroll
  for (int mi = 0; mi < 4; ++mi)
#pragma unroll
    for (int ni = 0; ni < 2; ++ni) {
      int p = p0 + wp + (ni << 5) + l31;
#pragma unroll
      for (int rg = 0; rg < 4; ++rg) {
        int m = m0 + wm + (mi << 5) + 8 * rg + 4 * hi8;
        const float4 sv = *(const float4*)(S + (size_t)p * DX + m);
        tracc += acc[mi][ni][rg * 4 + 0] * sv.x + acc[mi][ni][rg * 4 + 1] * sv.y +
                 acc[mi][ni][rg * 4 + 2] * sv.z + acc[mi][ni][rg * 4 + 3] * sv.w;
      }
    }
#pragma unroll
  for (int off = 32; off > 0; off >>= 1) tracc += __shfl_xor(tracc, off, 64);
  __syncthreads();
  if (lane == 0) ((float*)lds)[wv] = tracc;
  __syncthreads();
  if (t == 0) {
    float s = 0.f;
    for (int i = 0; i < 8; ++i) s += ((float*)lds)[i];
    part_tr[b * 16 + tile] = s;
  }
  __syncthreads();

  // ---- epilogue 2: Ah -> LDS [p][m] (swizzled) -> coalesced 16B stores ----
#pragma unroll
  for (int mi = 0; mi < 4; ++mi)
#pragma unroll
    for (int ni = 0; ni < 2; ++ni) {
      int p = wp + (ni << 5) + l31;
#pragma unroll
      for (int rg = 0; rg < 4; ++rg) {
        int m = wm + (mi << 5) + 8 * rg + 4 * hi8;
        unsigned int h0 = f2bf(acc[mi][ni][rg * 4 + 0]);
        unsigned int h1 = f2bf(acc[mi][ni][rg * 4 + 1]);
        unsigned int h2 = f2bf(acc[mi][ni][rg * 4 + 2]);
        unsigned int h3 = f2bf(acc[mi][ni][rg * 4 + 3]);
        int idx = p * 256 + (((m >> 3) ^ (p & 7)) << 3) + (m & 7);
        *(uint2*)&lds[idx] = make_uint2(h0 | (h1 << 16), h2 | (h3 << 16));
      }
    }
  __syncthreads();
#pragma unroll
  for (int i = 0; i < 16; ++i) {
    int cc = i * 512 + t;
    int row = cc >> 5, sl = cc & 31;
    int idx = row * 256 + ((sl ^ (row & 7)) << 3);
    uint4 v = *(const uint4*)&lds[idx];
    *(uint4*)(Ahg + ((size_t)(p0 + row) * NB + b) * DX + m0 + sl * 8) = v;
  }
}

// ---------------------------------------------------------------------------
// K2: numerator. One block per p: C[b,jk] += Ah[b,m]*R2[jk,m], K=1024.
// mc chunks of 64 m -> 45 KB LDS -> 3 blocks/CU. Pure gload16 staging,
// dbuf, per-wave counted vmcnt (waves 0-1: 6 loads/chunk, waves 2-3: 5).
// ---------------------------------------------------------------------------
__launch_bounds__(256)
__global__ void k2_contract(const ushort_t* __restrict__ R2,
                            const ushort_t* __restrict__ Ahg,
                            float* __restrict__ part_rho) {
  __shared__ ushort_t lds[22528];  // 2 bufs x (A 4096 | B 7168) ushorts
  int p = blockIdx.x;
  int t = threadIdx.x;
  int wv = t >> 6, lane = t & 63, lr = lane & 15, lg = lane >> 4;
  const ushort_t* R2p = R2 + (size_t)p * (112 * 1024);
  const ushort_t* Ahp = Ahg + (size_t)p * (NB * DX);

  f32x4 acc[7];
#pragma unroll
  for (int n = 0; n < 7; ++n)
#pragma unroll
    for (int i = 0; i < 4; ++i) acc[n][i] = 0.f;

  auto stage = [&](int mc) {
    int buf = (mc & 1) * 11264;
#pragma unroll
    for (int i = 0; i < 2; ++i) {
      int c = i * 256 + t;
      int br = c >> 3, sl = c & 7;
      int lsl = sl ^ (br & 7);
      gload16(Ahp + (size_t)br * DX + mc * 64 + lsl * 8,
              &lds[buf + (i * 256 + (t & ~63)) * 8]);
    }
#pragma unroll
    for (int i = 0; i < 4; ++i) {
      int c = i * 256 + t;
      if (c < 896) {
        int row = c >> 3, sl = c & 7;
        int lsl = sl ^ (row & 7);
        gload16(R2p + (size_t)row * 1024 + mc * 64 + lsl * 8,
                &lds[buf + 4096 + (i * 256 + (t & ~63)) * 8]);
      }
    }
  };

  stage(0);
#pragma unroll 1
  for (int mc = 0; mc < 16; ++mc) {
    int buf = (mc & 1) * 11264;
    if (mc < 15) {
      stage(mc + 1);
      if (wv < 2) { VMCNT6; } else { VMCNT5; }
    } else {
      VMCNT0;
    }
    __builtin_amdgcn_s_barrier();
    CFENCE;
#pragma unroll
    for (int s = 0; s < 2; ++s) {
      int slot = s * 4 + lg;
      int ra = 16 * wv + lr;
      short8 af = *(const short8*)&lds[buf + ra * 64 + ((slot ^ (ra & 7)) << 3)];
      __builtin_amdgcn_s_setprio(1);
#pragma unroll
      for (int n = 0; n < 7; ++n) {
        int rb = 16 * n + lr;
        short8 bf = *(const short8*)&lds[buf + 4096 + rb * 64 + ((slot ^ (rb & 7)) << 3)];
        acc[n] = __builtin_amdgcn_mfma_f32_16x16x32_bf16(af, bf, acc[n], 0, 0, 0);
      }
      __builtin_amdgcn_s_setprio(0);
    }
    CFENCE;
    __builtin_amdgcn_s_barrier();
  }
#pragma unroll
  for (int n = 0; n < 7; ++n) {
    int col = 16 * n + lr;
    if (col < NJK) {
#pragma unroll
      for (int i = 0; i < 4; ++i) {
        int b_ = 16 * wv + lg * 4 + i;
        part_rho[((size_t)p * NB + b_) * NJK + col] = acc[n][i];
      }
    }
  }
}

// ---------------------------------------------------------------------------
// K3a: partial p-reduction; K3b: finish + divide by EXACT trace.
// ---------------------------------------------------------------------------
__launch_bounds__(128)
__global__ void k3a(const float* __restrict__ part_rho, float* __restrict__ ws2) {
  int blk = blockIdx.x;  // 128 = 64 b x 2 halves
  int b = blk >> 1, h = blk & 1;
  int t = threadIdx.x;
  if (t >= NJK) return;
  float s = 0.f;
  for (int pp = 0; pp < 512; ++pp)
    s += part_rho[((size_t)(h * 512 + pp) * NB + b) * NJK + t];
  ws2[(size_t)(h * NB + b) * 128 + t] = s;
}

__launch_bounds__(128)
__global__ void k3b(const float* __restrict__ ws2, const float* __restrict__ part_tr,
                    float* __restrict__ out) {
  int b = blockIdx.x;
  int t = threadIdx.x;
  float tr = 0.f;
#pragma unroll
  for (int i = 0; i < 16; ++i) tr += part_tr[b * 16 + i];
  if (t < NJK) {
    float v = ws2[(size_t)b * 128 + t] + ws2[(size_t)(NB + b) * 128 + t];
    out[b * NJK + t] = v / tr;
  }
}

extern "C" void kernel_launch(void* const* d_in, const int* in_sizes, int n_in,
                              void* d_out, int out_size, void* d_ws, size_t ws_size,
                              hipStream_t stream) {
  const float* X = (const float*)d_in[0];
  const float* rho = (const float*)d_in[1];
  float* out = (float*)d_out;
  char* ws = (char*)d_ws;

  const size_t MB = 1048576ull;
  const size_t need_big = 868 * MB + 65536;
  const size_t need_small = 484 * MB + 65536;

  if (ws_size >= need_big) {
    ushort_t* XHL = (ushort_t*)(ws);              // 256 MiB
    ushort_t* XtHL = (ushort_t*)(ws + 256 * MB);  // 256 MiB
    ushort_t* Ahg = (ushort_t*)(ws + 512 * MB);   // 128 MiB
    ushort_t* R2 = (ushort_t*)(ws + 640 * MB);    // 224 MiB
    float* S = (float*)(ws + 864 * MB);           // 4 MiB
    float* part_tr = (float*)(ws + 868 * MB);     // 4 KiB
    float* part_rho = (float*)(ws);               // overlays XHL (dead after k1)
    float* ws2 = (float*)(ws + 32 * MB);

    hipLaunchKernelGGL(p0_rho, dim3(1024), dim3(256), 0, stream, rho, R2, S);
    hipLaunchKernelGGL(p0_split, dim3(16384), dim3(256), 0, stream, X, XHL, XtHL);
    hipLaunchKernelGGL(k1_gemm, dim3(1024), dim3(512), 0, stream, XHL, XtHL, S, Ahg, part_tr, 0);
    hipLaunchKernelGGL(k2_contract, dim3(1024), dim3(256), 0, stream, R2, Ahg, part_rho);
    hipLaunchKernelGGL(k3a, dim3(128), dim3(128), 0, stream, part_rho, ws2);
    hipLaunchKernelGGL(k3b, dim3(64), dim3(128), 0, stream, ws2, part_tr, out);
  } else {
    ushort_t* XHL = (ushort_t*)(ws);              // 64 MiB (per 16-batch group)
    ushort_t* XtHL = (ushort_t*)(ws + 64 * MB);   // 64 MiB
    ushort_t* Ahg = (ushort_t*)(ws + 128 * MB);   // 128 MiB
    ushort_t* R2 = (ushort_t*)(ws + 256 * MB);    // 224 MiB
    float* S = (float*)(ws + 480 * MB);           // 4 MiB
    float* part_tr = (float*)(ws + 484 * MB);     // 4 KiB
    float* part_rho = (float*)(ws);               // overlays XHL
    float* ws2 = (float*)(ws + 32 * MB);
    if (ws_size < need_small) return;

    hipLaunchKernelGGL(p0_rho, dim3(1024), dim3(256), 0, stream, rho, R2, S);
    for (int g = 0; g < 4; ++g) {
      hipLaunchKernelGGL(p0_split, dim3(4096), dim3(256), 0, stream,
                         X + (size_t)g * 16 * DX * DX, XHL, XtHL);
      hipLaunchKernelGGL(k1_gemm, dim3(256), dim3(512), 0, stream, XHL, XtHL, S, Ahg, part_tr, g * 16);
    }
    hipLaunchKernelGGL(k2_contract, dim3(1024), dim3(256), 0, stream, R2, Ahg, part_rho);
    hipLaunchKernelGGL(k3a, dim3(128), dim3(128), 0, stream, part_rho, ws2);
    hipLaunchKernelGGL(k3b, dim3(64), dim3(128), 0, stream, ws2, part_tr, out);
  }
}

// Round 10
// 730.802 us; speedup vs baseline: 1.1281x; 1.0093x over previous
//
#include <hip/hip_runtime.h>
#include <stdint.h>

#define DX 1024
#define NB 64
#define DY 10
#define NJK 100

typedef unsigned short ushort_t;
typedef __attribute__((ext_vector_type(8))) short short8;
typedef __attribute__((ext_vector_type(4))) float f32x4;
typedef __attribute__((ext_vector_type(16))) float f32x16;

#define VMCNT6 asm volatile("s_waitcnt vmcnt(6)" ::: "memory")
#define VMCNT5 asm volatile("s_waitcnt vmcnt(5)" ::: "memory")
#define VMCNT4 asm volatile("s_waitcnt vmcnt(4)" ::: "memory")
#define VMCNT0 asm volatile("s_waitcnt vmcnt(0)" ::: "memory")
#define LGKM0 asm volatile("s_waitcnt lgkmcnt(0)" ::: "memory")
#define CFENCE asm volatile("" ::: "memory")

__device__ __forceinline__ unsigned short f2bf(float f) {
  unsigned int u = __builtin_bit_cast(unsigned int, f);
  u += 0x7fffu + ((u >> 16) & 1u);
  return (unsigned short)(u >> 16);
}
__device__ __forceinline__ float bf2f(unsigned short h) {
  unsigned int u = ((unsigned int)h) << 16;
  return __builtin_bit_cast(float, u);
}
__device__ __forceinline__ void gload16(const void* g, void* l) {
  __builtin_amdgcn_global_load_lds((const __attribute__((address_space(1))) unsigned int*)g,
                                   (__attribute__((address_space(3))) unsigned int*)l, 16, 0, 0);
}

// ---------------------------------------------------------------------------
// P0rho: one pass over rho per p:
//   R2[p][jk(112 pad)][m(1024)] bf16 (plain slots, 224 MiB)
//   S[p][m] = sum_j rho[p][j][m][j]  (f32, fused diagonal, shfl-paired)
// ---------------------------------------------------------------------------
__launch_bounds__(256)
__global__ void p0_rho(const float* __restrict__ rho, ushort_t* __restrict__ R2,
                       float* __restrict__ S) {
  __shared__ ushort_t R_s[112 * 128];
  int p = blockIdx.x;
  int t = threadIdx.x;
  const float* rp = rho + (size_t)p * (DY * DX * DY);
  ushort_t* R2p = R2 + (size_t)p * (112 * 1024);
  int m = t >> 1, h = t & 1;

  for (int mc = 0; mc < 8; ++mc) {
    __syncthreads();
    float ssum = 0.f;
#pragma unroll
    for (int j = 0; j < DY; ++j) {
      const float* bj = rp + (size_t)j * (DX * DY) + (size_t)(mc * 128 + m) * DY;
      const float4 q = *(const float4*)(bj + h * 4);
      const float e = bj[8 + h];
      int rb = j * DY + h * 4;
      R_s[((rb + 0) * 128 + m) ^ (((rb + 0) & 15) << 3)] = f2bf(q.x);
      R_s[((rb + 1) * 128 + m) ^ (((rb + 1) & 15) << 3)] = f2bf(q.y);
      R_s[((rb + 2) * 128 + m) ^ (((rb + 2) & 15) << 3)] = f2bf(q.z);
      R_s[((rb + 3) * 128 + m) ^ (((rb + 3) & 15) << 3)] = f2bf(q.w);
      int r8 = j * DY + 8 + h;
      R_s[(r8 * 128 + m) ^ ((r8 & 15) << 3)] = f2bf(e);
      if (h == 0) {
        if (j == 0) ssum += q.x;
        if (j == 1) ssum += q.y;
        if (j == 2) ssum += q.z;
        if (j == 3) ssum += q.w;
        if (j == 8) ssum += e;
      } else {
        if (j == 4) ssum += q.x;
        if (j == 5) ssum += q.y;
        if (j == 6) ssum += q.z;
        if (j == 7) ssum += q.w;
        if (j == 9) ssum += e;
      }
    }
    ssum += __shfl_xor(ssum, 1, 64);
    if (h == 0) S[(size_t)p * DX + mc * 128 + m] = ssum;
    __syncthreads();
#pragma unroll
    for (int i = 0; i < 7; ++i) {
      int c = i * 256 + t;
      int row = c >> 4, sl = c & 15;
      uint4 v = make_uint4(0u, 0u, 0u, 0u);
      if (row < NJK) v = *(const uint4*)&R_s[(row * 128 + sl * 8) ^ ((row & 15) << 3)];
      *(uint4*)(R2p + (size_t)row * 1024 + mc * 128 + sl * 8) = v;
    }
  }
}

// ---------------------------------------------------------------------------
// P0a: emit BOTH operands of K1 pre-split:
//  XHL [b][kt(32)][m(1024)][8 slots x 16B] : record = [Ah k0..31 | Al k0..31]
//  XtHL[b][kt(32)][p(1024)][8 slots x 16B] : same for X^T rows.
// ---------------------------------------------------------------------------
__launch_bounds__(256)
__global__ void p0_split(const float* __restrict__ X,
                         ushort_t* __restrict__ XHL, ushort_t* __restrict__ XtHL) {
  __shared__ float T[64][65];
  int blk = blockIdx.x;
  int bl = blk >> 8;
  int tt = blk & 255;
  int r0 = (tt >> 4) << 6;
  int c0 = (tt & 15) << 6;
  const float* Xb = X + (size_t)bl * DX * DX;
  int t = threadIdx.x;
  int r = t >> 4, c = t & 15;
#pragma unroll
  for (int s = 0; s < 4; ++s) {
    const float4 v = *(const float4*)(Xb + (size_t)(r0 + r + 16 * s) * DX + c0 + c * 4);
    T[r + 16 * s][c * 4 + 0] = v.x;
    T[r + 16 * s][c * 4 + 1] = v.y;
    T[r + 16 * s][c * 4 + 2] = v.z;
    T[r + 16 * s][c * 4 + 3] = v.w;
  }
  __syncthreads();
  int s8 = t & 7;
  int rw = t >> 3;
  int isLo = s8 >> 2, q = s8 & 3;
#pragma unroll
  for (int ktl = 0; ktl < 2; ++ktl) {
#pragma unroll
    for (int sp = 0; sp < 2; ++sp) {
      int loc = rw + sp * 32;
      {
        unsigned short hh8[8];
#pragma unroll
        for (int e = 0; e < 8; ++e) {
          float x = T[loc][ktl * 32 + q * 8 + e];
          unsigned short hh = f2bf(x);
          hh8[e] = isLo ? f2bf(x - bf2f(hh)) : hh;
        }
        int kt = (c0 >> 5) + ktl;
        size_t off = (((size_t)bl * 32 + kt) * 1024 + (r0 + loc)) * 64 + s8 * 8;
        uint4 v;
        v.x = (unsigned)hh8[0] | ((unsigned)hh8[1] << 16);
        v.y = (unsigned)hh8[2] | ((unsigned)hh8[3] << 16);
        v.z = (unsigned)hh8[4] | ((unsigned)hh8[5] << 16);
        v.w = (unsigned)hh8[6] | ((unsigned)hh8[7] << 16);
        *(uint4*)(XHL + off) = v;
      }
      {
        unsigned short hh8[8];
#pragma unroll
        for (int e = 0; e < 8; ++e) {
          float x = T[ktl * 32 + q * 8 + e][loc];
          unsigned short hh = f2bf(x);
          hh8[e] = isLo ? f2bf(x - bf2f(hh)) : hh;
        }
        int kt = (r0 >> 5) + ktl;
        size_t off = (((size_t)bl * 32 + kt) * 1024 + (c0 + loc)) * 64 + s8 * 8;
        uint4 v;
        v.x = (unsigned)hh8[0] | ((unsigned)hh8[1] << 16);
        v.y = (unsigned)hh8[2] | ((unsigned)hh8[3] << 16);
        v.z = (unsigned)hh8[4] | ((unsigned)hh8[5] << 16);
        v.w = (unsigned)hh8[6] | ((unsigned)hh8[7] << 16);
        *(uint4*)(XtHL + off) = v;
      }
    }
  }
}

// ---------------------------------------------------------------------------
// K1: A[b]=X[b]@X[b], 3-pass split-bf16, 256x256 tile, BK=32, 8 waves (2x4).
// 8-PHASE K-step: each phase {<=3 ds_read, <=2 gloads, barrier,
// lgkm0+sched_barrier, setprio, 6 MFMA}.  Stage A(kt+1)@ph0-1, B@ph2-3;
// drains vmcnt(4)@ph5 (A aged 4 ph), vmcnt(0)@ph7 (B aged 4 ph).
// ---------------------------------------------------------------------------
__launch_bounds__(512, 2)
__global__ void k1_gemm(const ushort_t* __restrict__ XHL,
                        const ushort_t* __restrict__ XtHL,
                        const float* __restrict__ S,
                        ushort_t* __restrict__ Ahg,
                        float* __restrict__ part_tr, int bg) {
  __shared__ ushort_t lds[65536];  // 2 bufs x (A 16384 | B 16384) ushorts
  int wg = blockIdx.x;
  int cpx = gridDim.x >> 3;
  int gt = (wg & 7) * cpx + (wg >> 3);  // XCD-chunked
  int bl = gt >> 4, tile = gt & 15;
  int b = bg + bl;
  int m0 = (tile >> 2) << 8, p0 = (tile & 3) << 8;
  int t = threadIdx.x;
  int wv = t >> 6, lane = t & 63, l31 = lane & 31, hi8 = lane >> 5;
  int wm = (wv >> 2) << 7, wp = (wv & 3) << 6;

  f32x16 acc[4][2];
#pragma unroll
  for (int mi = 0; mi < 4; ++mi)
#pragma unroll
    for (int ni = 0; ni < 2; ++ni)
#pragma unroll
      for (int e = 0; e < 16; ++e) acc[mi][ni][e] = 0.f;

  int lam = lane >> 3;
  int lsl = (lane & 7) ^ lam;
  const ushort_t* Asrc = XHL + ((size_t)bl * 32 * 1024 + m0) * 64 + (size_t)lsl * 8;
  const ushort_t* Bsrc = XtHL + ((size_t)bl * 32 * 1024 + p0) * 64 + (size_t)lsl * 8;
  int ldsw = (t & ~63) * 8;

  auto stageA2 = [&](int kt, int half) {
    int buf = (kt & 1) << 15;
    size_t ko = (size_t)kt * 65536;
#pragma unroll
    for (int i = half * 2; i < half * 2 + 2; ++i) {
      int rr = (i << 6) + (wv << 3) + lam;
      gload16(Asrc + ko + (size_t)rr * 64, &lds[buf + (i << 12) + ldsw]);
    }
  };
  auto stageB2 = [&](int kt, int half) {
    int buf = (kt & 1) << 15;
    size_t ko = (size_t)kt * 65536;
#pragma unroll
    for (int i = half * 2; i < half * 2 + 2; ++i) {
      int rr = (i << 6) + (wv << 3) + lam;
      gload16(Bsrc + ko + (size_t)rr * 64, &lds[buf + 16384 + (i << 12) + ldsw]);
    }
  };
  auto readB = [&](int buf, int kc, short8* bh, short8* blo) {
#pragma unroll
    for (int ni = 0; ni < 2; ++ni) {
      int p = wp + (ni << 5) + l31;
      int rowb = buf + 16384 + p * 64;
      bh[ni] = *(const short8*)&lds[rowb + (((kc * 2 + hi8) ^ (p & 7)) << 3)];
      blo[ni] = *(const short8*)&lds[rowb + (((4 + kc * 2 + hi8) ^ (p & 7)) << 3)];
    }
  };
  auto readA2 = [&](int buf, int kc, int mi, short8& a, short8& l) {
    int m = wm + (mi << 5) + l31;
    int rowa = buf + m * 64;
    a = *(const short8*)&lds[rowa + (((kc * 2 + hi8) ^ (m & 7)) << 3)];
    l = *(const short8*)&lds[rowa + (((4 + kc * 2 + hi8) ^ (m & 7)) << 3)];
  };
  auto mfma6 = [&](int mi, const short8& a, const short8& l,
                   const short8* bh, const short8* blo) {
    __builtin_amdgcn_s_setprio(1);
#pragma unroll
    for (int ni = 0; ni < 2; ++ni) {
      acc[mi][ni] = __builtin_amdgcn_mfma_f32_32x32x16_bf16(a, bh[ni], acc[mi][ni], 0, 0, 0);
      acc[mi][ni] = __builtin_amdgcn_mfma_f32_32x32x16_bf16(a, blo[ni], acc[mi][ni], 0, 0, 0);
      acc[mi][ni] = __builtin_amdgcn_mfma_f32_32x32x16_bf16(l, bh[ni], acc[mi][ni], 0, 0, 0);
    }
    __builtin_amdgcn_s_setprio(0);
  };

  // prologue: stage tile 0 fully, drain, sync
  stageA2(0, 0);
  stageA2(0, 1);
  stageB2(0, 0);
  stageB2(0, 1);
  VMCNT0;
  __builtin_amdgcn_s_barrier();

#pragma unroll 1
  for (int kt = 0; kt < 32; ++kt) {
    int buf = (kt & 1) << 15;
    short8 bh[2], blo[2], a, l;
    // ph0: readB(kc0)+A frag mi0; stage A(kt+1) half0
    readB(buf, 0, bh, blo);
    readA2(buf, 0, 0, a, l);
    if (kt < 31) stageA2(kt + 1, 0);
    CFENCE; __builtin_amdgcn_s_barrier(); LGKM0; __builtin_amdgcn_sched_barrier(0);
    mfma6(0, a, l, bh, blo);
    // ph1: A frag mi1; stage A(kt+1) half1
    readA2(buf, 0, 1, a, l);
    if (kt < 31) stageA2(kt + 1, 1);
    CFENCE; __builtin_amdgcn_s_barrier(); LGKM0; __builtin_amdgcn_sched_barrier(0);
    mfma6(1, a, l, bh, blo);
    // ph2: A frag mi2; stage B(kt+1) half0
    readA2(buf, 0, 2, a, l);
    if (kt < 31) stageB2(kt + 1, 0);
    CFENCE; __builtin_amdgcn_s_barrier(); LGKM0; __builtin_amdgcn_sched_barrier(0);
    mfma6(2, a, l, bh, blo);
    // ph3: A frag mi3; stage B(kt+1) half1
    readA2(buf, 0, 3, a, l);
    if (kt < 31) stageB2(kt + 1, 1);
    CFENCE; __builtin_amdgcn_s_barrier(); LGKM0; __builtin_amdgcn_sched_barrier(0);
    mfma6(3, a, l, bh, blo);
    // ph4: readB(kc1)+A frag mi0
    readB(buf, 1, bh, blo);
    readA2(buf, 1, 0, a, l);
    CFENCE; __builtin_amdgcn_s_barrier(); LGKM0; __builtin_amdgcn_sched_barrier(0);
    mfma6(0, a, l, bh, blo);
    // ph5: A frag mi1; vmcnt(4): A(kt+1) landed (aged 4 phases)
    readA2(buf, 1, 1, a, l);
    if (kt < 31) { VMCNT4; }
    CFENCE; __builtin_amdgcn_s_barrier(); LGKM0; __builtin_amdgcn_sched_barrier(0);
    mfma6(1, a, l, bh, blo);
    // ph6: A frag mi2
    readA2(buf, 1, 2, a, l);
    CFENCE; __builtin_amdgcn_s_barrier(); LGKM0; __builtin_amdgcn_sched_barrier(0);
    mfma6(2, a, l, bh, blo);
    // ph7: A frag mi3; vmcnt(0): B(kt+1) landed (aged 4 phases)
    readA2(buf, 1, 3, a, l);
    VMCNT0;
    CFENCE; __builtin_amdgcn_s_barrier(); LGKM0; __builtin_amdgcn_sched_barrier(0);
    mfma6(3, a, l, bh, blo);
  }

  // ---- epilogue 1: EXACT trace partial from f32 accumulator ----
  float tracc = 0.f;
#pragma unroll
  for (int mi = 0; mi < 4; ++mi)
#pragma unroll
    for (int ni = 0; ni < 2; ++ni) {
      int p = p0 + wp + (ni << 5) + l31;
#pragma unroll
      for (int rg = 0; rg < 4; ++rg) {
        int m = m0 + wm + (mi << 5) + 8 * rg + 4 * hi8;
        const float4 sv = *(const float4*)(S + (size_t)p * DX + m);
        tracc += acc[mi][ni][rg * 4 + 0] * sv.x + acc[mi][ni][rg * 4 + 1] * sv.y +
                 acc[mi][ni][rg * 4 + 2] * sv.z + acc[mi][ni][rg * 4 + 3] * sv.w;
      }
    }
#pragma unroll
  for (int off = 32; off > 0; off >>= 1) tracc += __shfl_xor(tracc, off, 64);
  __syncthreads();
  if (lane == 0) ((float*)lds)[wv] = tracc;
  __syncthreads();
  if (t == 0) {
    float s = 0.f;
    for (int i = 0; i < 8; ++i) s += ((float*)lds)[i];
    part_tr[b * 16 + tile] = s;
  }
  __syncthreads();

  // ---- epilogue 2: Ah -> LDS [p][m] (swizzled) -> coalesced 16B stores ----
#pragma unroll
  for (int mi = 0; mi < 4; ++mi)
#pragma unroll
    for (int ni = 0; ni < 2; ++ni) {
      int p = wp + (ni << 5) + l31;
#pragma unroll
      for (int rg = 0; rg < 4; ++rg) {
        int m = wm + (mi << 5) + 8 * rg + 4 * hi8;
        unsigned int h0 = f2bf(acc[mi][ni][rg * 4 + 0]);
        unsigned int h1 = f2bf(acc[mi][ni][rg * 4 + 1]);
        unsigned int h2 = f2bf(acc[mi][ni][rg * 4 + 2]);
        unsigned int h3 = f2bf(acc[mi][ni][rg * 4 + 3]);
        int idx = p * 256 + (((m >> 3) ^ (p & 7)) << 3) + (m & 7);
        *(uint2*)&lds[idx] = make_uint2(h0 | (h1 << 16), h2 | (h3 << 16));
      }
    }
  __syncthreads();
#pragma unroll
  for (int i = 0; i < 16; ++i) {
    int cc = i * 512 + t;
    int row = cc >> 5, sl = cc & 31;
    int idx = row * 256 + ((sl ^ (row & 7)) << 3);
    uint4 v = *(const uint4*)&lds[idx];
    *(uint4*)(Ahg + ((size_t)(p0 + row) * NB + b) * DX + m0 + sl * 8) = v;
  }
}

// ---------------------------------------------------------------------------
// K2: numerator. One block per p: C[b,jk] += Ah[b,m]*R2[jk,m], K=1024.
// ---------------------------------------------------------------------------
__launch_bounds__(256)
__global__ void k2_contract(const ushort_t* __restrict__ R2,
                            const ushort_t* __restrict__ Ahg,
                            float* __restrict__ part_rho) {
  __shared__ ushort_t lds[22528];
  int p = blockIdx.x;
  int t = threadIdx.x;
  int wv = t >> 6, lane = t & 63, lr = lane & 15, lg = lane >> 4;
  const ushort_t* R2p = R2 + (size_t)p * (112 * 1024);
  const ushort_t* Ahp = Ahg + (size_t)p * (NB * DX);

  f32x4 acc[7];
#pragma unroll
  for (int n = 0; n < 7; ++n)
#pragma unroll
    for (int i = 0; i < 4; ++i) acc[n][i] = 0.f;

  auto stage = [&](int mc) {
    int buf = (mc & 1) * 11264;
#pragma unroll
    for (int i = 0; i < 2; ++i) {
      int c = i * 256 + t;
      int br = c >> 3, sl = c & 7;
      int lsl = sl ^ (br & 7);
      gload16(Ahp + (size_t)br * DX + mc * 64 + lsl * 8,
              &lds[buf + (i * 256 + (t & ~63)) * 8]);
    }
#pragma unroll
    for (int i = 0; i < 4; ++i) {
      int c = i * 256 + t;
      if (c < 896) {
        int row = c >> 3, sl = c & 7;
        int lsl = sl ^ (row & 7);
        gload16(R2p + (size_t)row * 1024 + mc * 64 + lsl * 8,
                &lds[buf + 4096 + (i * 256 + (t & ~63)) * 8]);
      }
    }
  };

  stage(0);
#pragma unroll 1
  for (int mc = 0; mc < 16; ++mc) {
    int buf = (mc & 1) * 11264;
    if (mc < 15) {
      stage(mc + 1);
      if (wv < 2) { VMCNT6; } else { VMCNT5; }
    } else {
      VMCNT0;
    }
    __builtin_amdgcn_s_barrier();
    CFENCE;
#pragma unroll
    for (int s = 0; s < 2; ++s) {
      int slot = s * 4 + lg;
      int ra = 16 * wv + lr;
      short8 af = *(const short8*)&lds[buf + ra * 64 + ((slot ^ (ra & 7)) << 3)];
      __builtin_amdgcn_s_setprio(1);
#pragma unroll
      for (int n = 0; n < 7; ++n) {
        int rb = 16 * n + lr;
        short8 bf = *(const short8*)&lds[buf + 4096 + rb * 64 + ((slot ^ (rb & 7)) << 3)];
        acc[n] = __builtin_amdgcn_mfma_f32_16x16x32_bf16(af, bf, acc[n], 0, 0, 0);
      }
      __builtin_amdgcn_s_setprio(0);
    }
    CFENCE;
    __builtin_amdgcn_s_barrier();
  }
#pragma unroll
  for (int n = 0; n < 7; ++n) {
    int col = 16 * n + lr;
    if (col < NJK) {
#pragma unroll
      for (int i = 0; i < 4; ++i) {
        int b_ = 16 * wv + lg * 4 + i;
        part_rho[((size_t)p * NB + b_) * NJK + col] = acc[n][i];
      }
    }
  }
}

// ---------------------------------------------------------------------------
// K3a: partial p-reduction; K3b: finish + divide by EXACT trace.
// ---------------------------------------------------------------------------
__launch_bounds__(128)
__global__ void k3a(const float* __restrict__ part_rho, float* __restrict__ ws2) {
  int blk = blockIdx.x;
  int b = blk >> 1, h = blk & 1;
  int t = threadIdx.x;
  if (t >= NJK) return;
  float s = 0.f;
  for (int pp = 0; pp < 512; ++pp)
    s += part_rho[((size_t)(h * 512 + pp) * NB + b) * NJK + t];
  ws2[(size_t)(h * NB + b) * 128 + t] = s;
}

__launch_bounds__(128)
__global__ void k3b(const float* __restrict__ ws2, const float* __restrict__ part_tr,
                    float* __restrict__ out) {
  int b = blockIdx.x;
  int t = threadIdx.x;
  float tr = 0.f;
#pragma unroll
  for (int i = 0; i < 16; ++i) tr += part_tr[b * 16 + i];
  if (t < NJK) {
    float v = ws2[(size_t)b * 128 + t] + ws2[(size_t)(NB + b) * 128 + t];
    out[b * NJK + t] = v / tr;
  }
}

extern "C" void kernel_launch(void* const* d_in, const int* in_sizes, int n_in,
                              void* d_out, int out_size, void* d_ws, size_t ws_size,
                              hipStream_t stream) {
  const float* X = (const float*)d_in[0];
  const float* rho = (const float*)d_in[1];
  float* out = (float*)d_out;
  char* ws = (char*)d_ws;

  const size_t MB = 1048576ull;
  const size_t need_big = 868 * MB + 65536;
  const size_t need_small = 484 * MB + 65536;

  if (ws_size >= need_big) {
    ushort_t* XHL = (ushort_t*)(ws);              // 256 MiB
    ushort_t* XtHL = (ushort_t*)(ws + 256 * MB);  // 256 MiB
    ushort_t* Ahg = (ushort_t*)(ws + 512 * MB);   // 128 MiB
    ushort_t* R2 = (ushort_t*)(ws + 640 * MB);    // 224 MiB
    float* S = (float*)(ws + 864 * MB);           // 4 MiB
    float* part_tr = (float*)(ws + 868 * MB);     // 4 KiB
    float* part_rho = (float*)(ws);               // overlays XHL (dead after k1)
    float* ws2 = (float*)(ws + 32 * MB);

    hipLaunchKernelGGL(p0_rho, dim3(1024), dim3(256), 0, stream, rho, R2, S);
    hipLaunchKernelGGL(p0_split, dim3(16384), dim3(256), 0, stream, X, XHL, XtHL);
    hipLaunchKernelGGL(k1_gemm, dim3(1024), dim3(512), 0, stream, XHL, XtHL, S, Ahg, part_tr, 0);
    hipLaunchKernelGGL(k2_contract, dim3(1024), dim3(256), 0, stream, R2, Ahg, part_rho);
    hipLaunchKernelGGL(k3a, dim3(128), dim3(128), 0, stream, part_rho, ws2);
    hipLaunchKernelGGL(k3b, dim3(64), dim3(128), 0, stream, ws2, part_tr, out);
  } else {
    ushort_t* XHL = (ushort_t*)(ws);
    ushort_t* XtHL = (ushort_t*)(ws + 64 * MB);
    ushort_t* Ahg = (ushort_t*)(ws + 128 * MB);
    ushort_t* R2 = (ushort_t*)(ws + 256 * MB);
    float* S = (float*)(ws + 480 * MB);
    float* part_tr = (float*)(ws + 484 * MB);
    float* part_rho = (float*)(ws);
    float* ws2 = (float*)(ws + 32 * MB);
    if (ws_size < need_small) return;

    hipLaunchKernelGGL(p0_rho, dim3(1024), dim3(256), 0, stream, rho, R2, S);
    for (int g = 0; g < 4; ++g) {
      hipLaunchKernelGGL(p0_split, dim3(4096), dim3(256), 0, stream,
                         X + (size_t)g * 16 * DX * DX, XHL, XtHL);
      hipLaunchKernelGGL(k1_gemm, dim3(256), dim3(512), 0, stream, XHL, XtHL, S, Ahg, part_tr, g * 16);
    }
    hipLaunchKernelGGL(k2_contract, dim3(1024), dim3(256), 0, stream, R2, Ahg, part_rho);
    hipLaunchKernelGGL(k3a, dim3(128), dim3(128), 0, stream, part_rho, ws2);
    hipLaunchKernelGGL(k3b, dim3(64), dim3(128), 0, stream, ws2, part_tr, out);
  }
}